// Round 7
// baseline (477.698 us; speedup 1.0000x reference)
//
#include <hip/hip_runtime.h>
#include <hip/hip_bf16.h>
#include <stdint.h>

// Problem constants
#define B_   2
#define S_   2048
#define H_   2048
#define NH_  16
#define HD_  128
#define MTOK 4096      // B*S
#define NQKV 6144      // 3*H

typedef unsigned short u16;
typedef __attribute__((ext_vector_type(8))) __bf16 bf16x8;
typedef __attribute__((ext_vector_type(4))) float f32x4;
typedef __attribute__((ext_vector_type(16))) float f32x16;

static __device__ __forceinline__ float bf2f(u16 u){
  union { uint32_t i; float f; } v; v.i = ((uint32_t)u) << 16; return v.f;
}
static __device__ __forceinline__ u16 f2bf(float f){
  union { float f; uint32_t i; } v; v.f = f;
  uint32_t r = v.i + 0x7FFFu + ((v.i >> 16) & 1u);   // RNE
  return (u16)(r >> 16);
}
static __device__ __forceinline__ uint32_t cvt_pk_bf16(float lo, float hi){
  uint32_t r;
  asm("v_cvt_pk_bf16_f32 %0, %1, %2" : "=v"(r) : "v"(lo), "v"(hi));
  return r;
}
static __device__ __forceinline__ void pl32swap(uint32_t &a, uint32_t &b){
  asm volatile("v_permlane32_swap_b32 %0, %1" : "+v"(a), "+v"(b));
}

__device__ __forceinline__ void gload_lds16(const void* g, void* l){
  __builtin_amdgcn_global_load_lds((const __attribute__((address_space(1))) void*)g,
                                   (__attribute__((address_space(3))) void*)l, 16, 0, 0);
}

#define BARR  __builtin_amdgcn_s_barrier()
#define SCHB0 __builtin_amdgcn_sched_barrier(0)
#define VMW4  do{ asm volatile("s_waitcnt vmcnt(4)" ::: "memory"); SCHB0; }while(0)
#define VMW0  do{ asm volatile("s_waitcnt vmcnt(0)" ::: "memory"); SCHB0; }while(0)

// ---------- absmean (deterministic two-stage) ----------
__global__ void absum_kernel(const float* __restrict__ w, int n, float* __restrict__ partial){
  __shared__ float sm[256];
  float s = 0.f;
  for (int i = blockIdx.x*256 + threadIdx.x; i < n; i += gridDim.x*256)
    s += fabsf(w[i]);
  sm[threadIdx.x] = s; __syncthreads();
  for (int st = 128; st > 0; st >>= 1){
    if ((int)threadIdx.x < st) sm[threadIdx.x] += sm[threadIdx.x + st];
    __syncthreads();
  }
  if (threadIdx.x == 0) partial[blockIdx.x] = sm[0];
}

__global__ void finalize_kernel(const float* __restrict__ p1, const float* __restrict__ p2,
                                float* __restrict__ scales){
  __shared__ double sm[256];
  int t = threadIdx.x;
  double s = (double)p1[t] + (double)p1[t+256] + (double)p1[t+512] + (double)p1[t+768];
  sm[t] = s; __syncthreads();
  for (int st = 128; st > 0; st >>= 1){ if (t < st) sm[t] += sm[t+st]; __syncthreads(); }
  if (t == 0) scales[0] = (float)(1.0 / (sm[0] / (double)(3*H_*H_) + 1e-5));
  __syncthreads();
  s = (double)p2[t] + (double)p2[t+256] + (double)p2[t+512] + (double)p2[t+768];
  sm[t] = s; __syncthreads();
  for (int st = 128; st > 0; st >>= 1){ if (t < st) sm[t] += sm[t+st]; __syncthreads(); }
  if (t == 0) scales[1] = (float)(1.0 / (sm[0] / (double)(H_*H_) + 1e-5));
}

// ---------- ternary quantize to bf16 {-1,0,1} ----------
__global__ void quant_kernel(const float* __restrict__ w, u16* __restrict__ wq, int n,
                             const float* __restrict__ scales, int which){
  float inv = scales[which];
  for (int i = blockIdx.x*256 + threadIdx.x; i < n; i += gridDim.x*256){
    float q = rintf(w[i] * inv);
    q = fminf(1.f, fmaxf(-1.f, q));
    wq[i] = f2bf(q);
  }
}

__global__ void castx_kernel(const float* __restrict__ x, u16* __restrict__ xb, int n){
  int i = blockIdx.x*256 + threadIdx.x;
  if (i < n) xb[i] = f2bf(x[i]);
}

// ---------- GEMM C = A * B^T, 128x128 tile, BK=32, 4 waves ----------
// R4 frame + (1) frag-ordered LDS (1KB frags, ds_read = fragbase + lane*16B ->
// zero bank conflicts; gload_lds dest linear, global src pre-permuted) and
// (2) T3-minimum prefetch double-buffer: STAGE(t+1) issued BEFORE computing
// tile t, counted vmcnt(4) + raw barrier (invariant: 4 loads in flight at
// iter top = next tile's stage). Never vmcnt(0) until the last iteration.
template<int EPI>
__global__ __launch_bounds__(256) void gemm_kernel(const u16* __restrict__ A,
    const u16* __restrict__ Bw, int M, int N, int K,
    float* __restrict__ outf, u16* __restrict__ qb, u16* __restrict__ kb, u16* __restrict__ vtb)
{
  __shared__ alignas(16) u16 As[2][4096];   // 8 frags x 512 u16 per buf
  __shared__ alignas(16) u16 Bs[2][4096];
  int nbm = M >> 7;
  int nb_tot = nbm * (N >> 7);
  int bid = blockIdx.x;
  int chunk = nb_tot >> 3;                  // grids divisible by 8
  int sb = (bid & 7)*chunk + (bid >> 3);    // XCD-contiguous swizzle (bijective)
  int bm = sb % nbm, bn = sb / nbm;         // col-major within XCD chunk (B reuse)
  int m0 = bm << 7, n0 = bn << 7;
  int tid = threadIdx.x;
  int lane = tid & 63, wid = tid >> 6;
  int wr = wid >> 1, wc = wid & 1;
  int lr = lane & 15, lg = lane >> 4;
  int lg8 = lg << 3;

  const u16* Ab = A + (size_t)m0 * K;
  const u16* Bb = Bw + (size_t)n0 * K;

  f32x4 acc[4][4];
  #pragma unroll
  for (int i = 0; i < 4; i++)
    #pragma unroll
    for (int j = 0; j < 4; j++) acc[i][j] = f32x4{0.f,0.f,0.f,0.f};

  // stage tile at k0 into buf: frag fa = 16 rows x 32 k, lane(lr,lg)<->[lr][lg*8]
  auto STAGE = [&](int buf, int k0){
    #pragma unroll
    for (int j = 0; j < 2; j++){
      int fa = wid*2 + j;                   // 0..7
      gload_lds16(Ab + (size_t)(fa*16 + lr)*K + k0 + lg8, &As[buf][fa*512 + lane*8]);
      gload_lds16(Bb + (size_t)(fa*16 + lr)*K + k0 + lg8, &Bs[buf][fa*512 + lane*8]);
    }
  };

  int NT = K >> 5;                          // 64
  STAGE(0, 0);
  for (int t = 0; t < NT; t++){
    int buf = t & 1;
    if (t + 1 < NT){ STAGE(buf ^ 1, (t + 1) << 5); VMW4; }
    else           { VMW0; }
    BARR;
    bf16x8 af[4], bfr[4];
    #pragma unroll
    for (int mi = 0; mi < 4; mi++) af[mi]  = *(const bf16x8*)(&As[buf][(wr*4 + mi)*512 + lane*8]);
    #pragma unroll
    for (int ni = 0; ni < 4; ni++) bfr[ni] = *(const bf16x8*)(&Bs[buf][(wc*4 + ni)*512 + lane*8]);
    #pragma unroll
    for (int mi = 0; mi < 4; mi++)
      #pragma unroll
      for (int ni = 0; ni < 4; ni++)
        acc[mi][ni] = __builtin_amdgcn_mfma_f32_16x16x32_bf16(af[mi], bfr[ni], acc[mi][ni], 0, 0, 0);
    SCHB0;                                  // keep MFMAs (and their lgkm waits) before barrier
    BARR;
  }

  #pragma unroll
  for (int mi = 0; mi < 4; mi++){
    #pragma unroll
    for (int ni = 0; ni < 4; ni++){
      int ncol = n0 + wc*64 + ni*16 + lr;
      #pragma unroll
      for (int r = 0; r < 4; r++){
        int m = m0 + wr*64 + mi*16 + lg*4 + r;
        float v = acc[mi][ni][r] * 0.0625f;           // /16
        v = fminf(128.f, fmaxf(-128.f, v));
        if (EPI == 1){
          outf[(size_t)m*N + ncol] = v;
        } else {
          int b = m >> 11, s = m & 2047;
          int part = ncol >> 11, c = ncol & 2047;
          int h = c >> 7, d = c & 127;
          int bh = b*NH_ + h;
          u16 bv = f2bf(v);
          if (part == 0)      qb[((bh*S_ + s) << 7) + d] = bv;
          else if (part == 1) kb[((bh*S_ + s) << 7) + d] = bv;
          else                vtb[((bh*HD_ + d) << 11) + s] = bv;  // V transposed
        }
      }
    }
  }
}

// ---------- RoPE in place on q,k [B*NH, S, HD] ----------
__global__ void rope_kernel(u16* __restrict__ qb, u16* __restrict__ kb, const float* __restrict__ rot){
  int i = blockIdx.x*256 + threadIdx.x;
  int d = i & 63;
  int s = (i >> 6) & 2047;
  int bh = (i >> 17) & 31;
  u16* buf = (i >> 22) ? kb : qb;
  int base = (bh*S_ + s)*HD_;
  float c  = rot[s*HD_ + d];
  float sn = rot[S_*HD_ + s*HD_ + d];
  float x1 = bf2f(buf[base + d]);
  float x2 = bf2f(buf[base + d + 64]);
  buf[base + d]      = f2bf(x1*c - x2*sn);
  buf[base + d + 64] = f2bf(x2*c + x1*sn);
}

// ---------- causal flash attention: 4 waves x 32 q-rows, 32x32x16 MFMA ----------
__global__ __launch_bounds__(256) void attn_kernel(const u16* __restrict__ qb,
    const u16* __restrict__ kb, const u16* __restrict__ vtb, u16* __restrict__ ao)
{
  __shared__ alignas(16) u16 Ks[2][4096];
  __shared__ alignas(16) u16 Vs[2][4096];

  int bid = blockIdx.x;                     // 512 blocks
  int sbid = (bid & 7)*64 + (bid >> 3);     // XCD swizzle
  int bh = sbid >> 4;
  int bq = 15 - (sbid & 15);                // longest q-blocks dispatch first
  int tid = threadIdx.x;
  int wid = tid >> 6, lane = tid & 63;
  int l31 = lane & 31, hl = lane >> 5;
  int q0 = bq * 128;
  int qw = q0 + wid*32;
  int q  = qw + l31;

  const u16* Qp = qb + (size_t)(bh*S_ + qw)*HD_;
  const u16* Kp = kb + (size_t)bh*S_*HD_;
  const u16* Vt = vtb + (size_t)bh*HD_*S_;

  bf16x8 qf[8];
  #pragma unroll
  for (int t = 0; t < 8; t++)
    qf[t] = *(const bf16x8*)(Qp + l31*HD_ + t*16 + hl*8);

  f32x16 o[4];
  #pragma unroll
  for (int i = 0; i < 4; i++)
    #pragma unroll
    for (int j = 0; j < 16; j++) o[i][j] = 0.f;
  float m_r = -1e30f, l_r = 0.f;
  const float sm_scale = 0.08838834764831845f;

  auto STAGE = [&](int buf, int kt2){
    int t0 = wid*2;
    gload_lds16(Kp + (size_t)(kt2 + l31)*HD_ + (t0  )*16 + hl*8, &Ks[buf][((t0  )*64 + lane)*8]);
    gload_lds16(Kp + (size_t)(kt2 + l31)*HD_ + (t0+1)*16 + hl*8, &Ks[buf][((t0+1)*64 + lane)*8]);
    int v0 = wid*2, v1 = wid*2 + 1;
    gload_lds16(Vt + (size_t)((v0&3)*32 + l31)*S_ + kt2 + (v0>>2)*16 + hl*8, &Vs[buf][(v0*64 + lane)*8]);
    gload_lds16(Vt + (size_t)((v1&3)*32 + l31)*S_ + kt2 + (v1>>2)*16 + hl*8, &Vs[buf][(v1*64 + lane)*8]);
  };

  int n_it = 4*bq + 4;
  STAGE(0, 0);
  int cur = 0, kt = 0;
  for (int it = 0; it < n_it; ++it, kt += 32){
    if (it + 1 < n_it){
      STAGE(cur ^ 1, kt + 32);
      asm volatile("s_waitcnt vmcnt(4)" ::: "memory");
    } else {
      asm volatile("s_waitcnt vmcnt(0)" ::: "memory");
    }
    __builtin_amdgcn_sched_barrier(0);
    __builtin_amdgcn_s_barrier();

    if (kt <= qw){
      f32x16 sa;
      #pragma unroll
      for (int j = 0; j < 16; j++) sa[j] = 0.f;
      #pragma unroll
      for (int t = 0; t < 8; t++){
        bf16x8 kf = *(const bf16x8*)(&Ks[cur][(t*64 + lane)*8]);
        sa = __builtin_amdgcn_mfma_f32_32x32x16_bf16(kf, qf[t], sa, 0, 0, 0);
      }

      float sv[16];
      if (kt == qw){
        #pragma unroll
        for (int r = 0; r < 16; r++){
          int key = kt + (r&3) + 8*(r>>2) + 4*hl;
          sv[r] = (key > q) ? -1e30f : sa[r]*sm_scale;
        }
      } else {
        #pragma unroll
        for (int r = 0; r < 16; r++) sv[r] = sa[r]*sm_scale;
      }

      float pm = sv[0];
      #pragma unroll
      for (int r = 1; r < 16; r++) pm = fmaxf(pm, sv[r]);
      pm = fmaxf(pm, __shfl_xor(pm, 32));
      if (!__all(pm - m_r <= 8.f)){         // defer-max (T13)
        float mn = fmaxf(m_r, pm);
        float scl = __expf(m_r - mn);
        m_r = mn; l_r *= scl;
        #pragma unroll
        for (int i = 0; i < 4; i++)
          #pragma unroll
          for (int j = 0; j < 16; j++) o[i][j] *= scl;
      }
      float p[16];
      #pragma unroll
      for (int r = 0; r < 16; r++) p[r] = __expf(sv[r] - m_r);
      float ts = 0.f;
      #pragma unroll
      for (int r = 0; r < 16; r++) ts += p[r];
      ts += __shfl_xor(ts, 32);
      l_r += ts;

      uint32_t a0 = cvt_pk_bf16(p[0],  p[1]),  a1 = cvt_pk_bf16(p[2],  p[3]);
      uint32_t a2 = cvt_pk_bf16(p[4],  p[5]),  a3 = cvt_pk_bf16(p[6],  p[7]);
      uint32_t b0 = cvt_pk_bf16(p[8],  p[9]),  b1 = cvt_pk_bf16(p[10], p[11]);
      uint32_t b2 = cvt_pk_bf16(p[12], p[13]), b3 = cvt_pk_bf16(p[14], p[15]);
      pl32swap(a0, a2); pl32swap(a1, a3);
      pl32swap(b0, b2); pl32swap(b1, b3);
      union { uint32_t u[4]; bf16x8 v; } pf0, pf1;
      pf0.u[0]=a0; pf0.u[1]=a1; pf0.u[2]=a2; pf0.u[3]=a3;
      pf1.u[0]=b0; pf1.u[1]=b1; pf1.u[2]=b2; pf1.u[3]=b3;

      #pragma unroll
      for (int db = 0; db < 4; db++){
        bf16x8 vf0 = *(const bf16x8*)(&Vs[cur][((0*4 + db)*64 + lane)*8]);
        o[db] = __builtin_amdgcn_mfma_f32_32x32x16_bf16(vf0, pf0.v, o[db], 0, 0, 0);
        bf16x8 vf1 = *(const bf16x8*)(&Vs[cur][((1*4 + db)*64 + lane)*8]);
        o[db] = __builtin_amdgcn_mfma_f32_32x32x16_bf16(vf1, pf1.v, o[db], 0, 0, 0);
      }
      asm volatile("s_waitcnt lgkmcnt(0)" ::: "memory");
    }
    __builtin_amdgcn_sched_barrier(0);
    __builtin_amdgcn_s_barrier();
    cur ^= 1;
  }

  float inv = 1.f / l_r;
  int b = bh >> 4, hh = bh & 15;
  u16* orow = ao + (size_t)(b*S_ + q)*H_ + hh*HD_;
  #pragma unroll
  for (int db = 0; db < 4; db++){
    #pragma unroll
    for (int g = 0; g < 4; g++){
      ushort4 pk4;
      pk4.x = f2bf(o[db][4*g+0]*inv);
      pk4.y = f2bf(o[db][4*g+1]*inv);
      pk4.z = f2bf(o[db][4*g+2]*inv);
      pk4.w = f2bf(o[db][4*g+3]*inv);
      *(ushort4*)(orow + db*32 + g*8 + hl*4) = pk4;
    }
  }
}

extern "C" void kernel_launch(void* const* d_in, const int* in_sizes, int n_in,
                              void* d_out, int out_size, void* d_ws, size_t ws_size,
                              hipStream_t stream) {
  const float* x      = (const float*)d_in[0];
  const float* rotary = (const float*)d_in[1];
  const float* w_qkv  = (const float*)d_in[2];
  const float* w_o    = (const float*)d_in[3];
  float* out = (float*)d_out;

  char* wsb = (char*)d_ws;
  float* part_qkv = (float*)wsb;             // [1024]
  float* part_o   = part_qkv + 1024;         // [1024]
  float* scales   = part_o + 1024;           // [2]
  size_t off = 16384;
  u16* xb    = (u16*)(wsb + off); off += (size_t)MTOK*H_*2;
  u16* wqkvq = (u16*)(wsb + off); off += (size_t)NQKV*H_*2;
  u16* woq   = (u16*)(wsb + off); off += (size_t)H_*H_*2;
  u16* qbuf  = (u16*)(wsb + off); off += (size_t)B_*NH_*S_*HD_*2;
  u16* kbuf  = (u16*)(wsb + off); off += (size_t)B_*NH_*S_*HD_*2;
  u16* vtb   = (u16*)(wsb + off); off += (size_t)B_*NH_*S_*HD_*2;
  u16* ao    = (u16*)(wsb + off); off += (size_t)MTOK*H_*2;

  absum_kernel<<<1024, 256, 0, stream>>>(w_qkv, 3*H_*H_, part_qkv);
  absum_kernel<<<1024, 256, 0, stream>>>(w_o, H_*H_, part_o);
  finalize_kernel<<<1, 256, 0, stream>>>(part_qkv, part_o, scales);
  quant_kernel<<<4096, 256, 0, stream>>>(w_qkv, wqkvq, 3*H_*H_, scales, 0);
  quant_kernel<<<2048, 256, 0, stream>>>(w_o, woq, H_*H_, scales, 1);
  castx_kernel<<<(MTOK*H_)/256, 256, 0, stream>>>(x, xb, MTOK*H_);

  gemm_kernel<0><<<(MTOK/128)*(NQKV/128), 256, 0, stream>>>(xb, wqkvq, MTOK, NQKV, H_,
                                                            nullptr, qbuf, kbuf, vtb);
  rope_kernel<<<(2*B_*NH_*S_*64)/256, 256, 0, stream>>>(qbuf, kbuf, rotary);
  attn_kernel<<<B_*NH_*(S_/128), 256, 0, stream>>>(qbuf, kbuf, vtb, ao);
  gemm_kernel<1><<<(MTOK/128)*(H_/128), 256, 0, stream>>>(ao, woq, MTOK, H_, H_,
                                                          out, nullptr, nullptr, nullptr);
}

// Round 8
// 473.715 us; speedup vs baseline: 1.0084x; 1.0084x over previous
//
#include <hip/hip_runtime.h>
#include <hip/hip_bf16.h>
#include <stdint.h>

// Problem constants
#define B_   2
#define S_   2048
#define H_   2048
#define NH_  16
#define HD_  128
#define MTOK 4096      // B*S
#define NQKV 6144      // 3*H

typedef unsigned short u16;
typedef __attribute__((ext_vector_type(8))) __bf16 bf16x8;
typedef __attribute__((ext_vector_type(4))) float f32x4;
typedef __attribute__((ext_vector_type(16))) float f32x16;

static __device__ __forceinline__ float bf2f(u16 u){
  union { uint32_t i; float f; } v; v.i = ((uint32_t)u) << 16; return v.f;
}
static __device__ __forceinline__ u16 f2bf(float f){
  union { float f; uint32_t i; } v; v.f = f;
  uint32_t r = v.i + 0x7FFFu + ((v.i >> 16) & 1u);   // RNE
  return (u16)(r >> 16);
}
static __device__ __forceinline__ uint32_t cvt_pk_bf16(float lo, float hi){
  uint32_t r;
  asm("v_cvt_pk_bf16_f32 %0, %1, %2" : "=v"(r) : "v"(lo), "v"(hi));
  return r;
}
static __device__ __forceinline__ void pl32swap(uint32_t &a, uint32_t &b){
  asm volatile("v_permlane32_swap_b32 %0, %1" : "+v"(a), "+v"(b));
}

__device__ __forceinline__ void gload_lds16(const void* g, void* l){
  __builtin_amdgcn_global_load_lds((const __attribute__((address_space(1))) void*)g,
                                   (__attribute__((address_space(3))) void*)l, 16, 0, 0);
}

// ---------- absmean (deterministic two-stage) ----------
__global__ void absum_kernel(const float* __restrict__ w, int n, float* __restrict__ partial){
  __shared__ float sm[256];
  float s = 0.f;
  for (int i = blockIdx.x*256 + threadIdx.x; i < n; i += gridDim.x*256)
    s += fabsf(w[i]);
  sm[threadIdx.x] = s; __syncthreads();
  for (int st = 128; st > 0; st >>= 1){
    if ((int)threadIdx.x < st) sm[threadIdx.x] += sm[threadIdx.x + st];
    __syncthreads();
  }
  if (threadIdx.x == 0) partial[blockIdx.x] = sm[0];
}

__global__ void finalize_kernel(const float* __restrict__ p1, const float* __restrict__ p2,
                                float* __restrict__ scales){
  __shared__ double sm[256];
  int t = threadIdx.x;
  double s = (double)p1[t] + (double)p1[t+256] + (double)p1[t+512] + (double)p1[t+768];
  sm[t] = s; __syncthreads();
  for (int st = 128; st > 0; st >>= 1){ if (t < st) sm[t] += sm[t+st]; __syncthreads(); }
  if (t == 0) scales[0] = (float)(1.0 / (sm[0] / (double)(3*H_*H_) + 1e-5));
  __syncthreads();
  s = (double)p2[t] + (double)p2[t+256] + (double)p2[t+512] + (double)p2[t+768];
  sm[t] = s; __syncthreads();
  for (int st = 128; st > 0; st >>= 1){ if (t < st) sm[t] += sm[t+st]; __syncthreads(); }
  if (t == 0) scales[1] = (float)(1.0 / (sm[0] / (double)(H_*H_) + 1e-5));
}

// ---------- ternary quantize to bf16 {-1,0,1} ----------
__global__ void quant_kernel(const float* __restrict__ w, u16* __restrict__ wq, int n,
                             const float* __restrict__ scales, int which){
  float inv = scales[which];
  for (int i = blockIdx.x*256 + threadIdx.x; i < n; i += gridDim.x*256){
    float q = rintf(w[i] * inv);
    q = fminf(1.f, fmaxf(-1.f, q));
    wq[i] = f2bf(q);
  }
}

__global__ void castx_kernel(const float* __restrict__ x, u16* __restrict__ xb, int n){
  int i = blockIdx.x*256 + threadIdx.x;
  if (i < n) xb[i] = f2bf(x[i]);
}

// ---------- GEMM C = A * B^T, 128x128 tile, BK=64 single-buffer, 4 waves ----------
// R4 frame (stage -> __syncthreads -> compute -> __syncthreads; the fastest
// measured structure) with: (1) BK=64 => half the drains, 32 MFMA per drain;
// (2) frag-ordered LDS (1KB frags, ds_read = fragbase + lane*16B, zero bank
// conflicts -- verified R5-R7); (3) tightened operand liveness (bfr[4] + one
// af live) to reduce VGPR below the 128 combined cliff if possible.
template<int EPI>
__global__ __launch_bounds__(256) void gemm_kernel(const u16* __restrict__ A,
    const u16* __restrict__ Bw, int M, int N, int K,
    float* __restrict__ outf, u16* __restrict__ qb, u16* __restrict__ kb, u16* __restrict__ vtb)
{
  __shared__ alignas(16) u16 As[16*512];    // 16 frags x 1KB = 16KB
  __shared__ alignas(16) u16 Bs[16*512];
  int nbm = M >> 7;
  int nb_tot = nbm * (N >> 7);
  int bid = blockIdx.x;
  int chunk = nb_tot >> 3;                  // grids divisible by 8
  int sb = (bid & 7)*chunk + (bid >> 3);    // XCD-contiguous swizzle (bijective)
  int bm = sb % nbm, bn = sb / nbm;         // col-major within XCD chunk (B reuse)
  int m0 = bm << 7, n0 = bn << 7;
  int tid = threadIdx.x;
  int lane = tid & 63, wid = tid >> 6;
  int wr = wid >> 1, wc = wid & 1;
  int lr = lane & 15, lg = lane >> 4;
  int lg8 = lg << 3;

  const u16* Ab = A + (size_t)m0 * K;
  const u16* Bb = Bw + (size_t)n0 * K;

  f32x4 acc[4][4];
  #pragma unroll
  for (int i = 0; i < 4; i++)
    #pragma unroll
    for (int j = 0; j < 4; j++) acc[i][j] = f32x4{0.f,0.f,0.f,0.f};

  // frag f (0..15): rows (f>>1)*16 + lr, k-cols (f&1)*32 + lg*8 (of 64)
  auto STAGE = [&](int k0){
    #pragma unroll
    for (int j = 0; j < 4; j++){
      int f = j*4 + wid;
      int row = ((f >> 1) << 4) + lr;
      int col = k0 + ((f & 1) << 5) + lg8;
      gload_lds16(Ab + (size_t)row*K + col, &As[f*512 + lane*8]);
      gload_lds16(Bb + (size_t)row*K + col, &Bs[f*512 + lane*8]);
    }
  };

  int NT = K >> 6;                          // 32
  for (int t = 0; t < NT; t++){
    STAGE(t << 6);
    __syncthreads();
    #pragma unroll
    for (int ks = 0; ks < 2; ks++){
      bf16x8 bfr[4];
      #pragma unroll
      for (int ni = 0; ni < 4; ni++)
        bfr[ni] = *(const bf16x8*)(&Bs[(((wc*4 + ni)<<1) + ks)*512 + lane*8]);
      #pragma unroll
      for (int mi = 0; mi < 4; mi++){
        bf16x8 af = *(const bf16x8*)(&As[(((wr*4 + mi)<<1) + ks)*512 + lane*8]);
        #pragma unroll
        for (int ni = 0; ni < 4; ni++)
          acc[mi][ni] = __builtin_amdgcn_mfma_f32_16x16x32_bf16(af, bfr[ni], acc[mi][ni], 0, 0, 0);
      }
    }
    __syncthreads();
  }

  #pragma unroll
  for (int mi = 0; mi < 4; mi++){
    #pragma unroll
    for (int ni = 0; ni < 4; ni++){
      int ncol = n0 + wc*64 + ni*16 + lr;
      #pragma unroll
      for (int r = 0; r < 4; r++){
        int m = m0 + wr*64 + mi*16 + lg*4 + r;
        float v = acc[mi][ni][r] * 0.0625f;           // /16
        v = fminf(128.f, fmaxf(-128.f, v));
        if (EPI == 1){
          outf[(size_t)m*N + ncol] = v;
        } else {
          int b = m >> 11, s = m & 2047;
          int part = ncol >> 11, c = ncol & 2047;
          int h = c >> 7, d = c & 127;
          int bh = b*NH_ + h;
          u16 bv = f2bf(v);
          if (part == 0)      qb[((bh*S_ + s) << 7) + d] = bv;
          else if (part == 1) kb[((bh*S_ + s) << 7) + d] = bv;
          else                vtb[((bh*HD_ + d) << 11) + s] = bv;  // V transposed
        }
      }
    }
  }
}

// ---------- RoPE in place on q,k [B*NH, S, HD] ----------
__global__ void rope_kernel(u16* __restrict__ qb, u16* __restrict__ kb, const float* __restrict__ rot){
  int i = blockIdx.x*256 + threadIdx.x;
  int d = i & 63;
  int s = (i >> 6) & 2047;
  int bh = (i >> 17) & 31;
  u16* buf = (i >> 22) ? kb : qb;
  int base = (bh*S_ + s)*HD_;
  float c  = rot[s*HD_ + d];
  float sn = rot[S_*HD_ + s*HD_ + d];
  float x1 = bf2f(buf[base + d]);
  float x2 = bf2f(buf[base + d + 64]);
  buf[base + d]      = f2bf(x1*c - x2*sn);
  buf[base + d + 64] = f2bf(x2*c + x1*sn);
}

// ---------- causal flash attention: 4 waves x 32 q-rows, 32x32x16 MFMA ----------
__global__ __launch_bounds__(256) void attn_kernel(const u16* __restrict__ qb,
    const u16* __restrict__ kb, const u16* __restrict__ vtb, u16* __restrict__ ao)
{
  __shared__ alignas(16) u16 Ks[2][4096];
  __shared__ alignas(16) u16 Vs[2][4096];

  int bid = blockIdx.x;                     // 512 blocks
  int sbid = (bid & 7)*64 + (bid >> 3);     // XCD swizzle
  int bh = sbid >> 4;
  int bq = 15 - (sbid & 15);                // longest q-blocks dispatch first
  int tid = threadIdx.x;
  int wid = tid >> 6, lane = tid & 63;
  int l31 = lane & 31, hl = lane >> 5;
  int q0 = bq * 128;
  int qw = q0 + wid*32;
  int q  = qw + l31;

  const u16* Qp = qb + (size_t)(bh*S_ + qw)*HD_;
  const u16* Kp = kb + (size_t)bh*S_*HD_;
  const u16* Vt = vtb + (size_t)bh*HD_*S_;

  bf16x8 qf[8];
  #pragma unroll
  for (int t = 0; t < 8; t++)
    qf[t] = *(const bf16x8*)(Qp + l31*HD_ + t*16 + hl*8);

  f32x16 o[4];
  #pragma unroll
  for (int i = 0; i < 4; i++)
    #pragma unroll
    for (int j = 0; j < 16; j++) o[i][j] = 0.f;
  float m_r = -1e30f, l_r = 0.f;
  const float sm_scale = 0.08838834764831845f;

  auto STAGE = [&](int buf, int kt2){
    int t0 = wid*2;
    gload_lds16(Kp + (size_t)(kt2 + l31)*HD_ + (t0  )*16 + hl*8, &Ks[buf][((t0  )*64 + lane)*8]);
    gload_lds16(Kp + (size_t)(kt2 + l31)*HD_ + (t0+1)*16 + hl*8, &Ks[buf][((t0+1)*64 + lane)*8]);
    int v0 = wid*2, v1 = wid*2 + 1;
    gload_lds16(Vt + (size_t)((v0&3)*32 + l31)*S_ + kt2 + (v0>>2)*16 + hl*8, &Vs[buf][(v0*64 + lane)*8]);
    gload_lds16(Vt + (size_t)((v1&3)*32 + l31)*S_ + kt2 + (v1>>2)*16 + hl*8, &Vs[buf][(v1*64 + lane)*8]);
  };

  int n_it = 4*bq + 4;
  STAGE(0, 0);
  int cur = 0, kt = 0;
  for (int it = 0; it < n_it; ++it, kt += 32){
    if (it + 1 < n_it){
      STAGE(cur ^ 1, kt + 32);
      asm volatile("s_waitcnt vmcnt(4)" ::: "memory");
    } else {
      asm volatile("s_waitcnt vmcnt(0)" ::: "memory");
    }
    __builtin_amdgcn_sched_barrier(0);
    __builtin_amdgcn_s_barrier();

    if (kt <= qw){
      f32x16 sa;
      #pragma unroll
      for (int j = 0; j < 16; j++) sa[j] = 0.f;
      #pragma unroll
      for (int t = 0; t < 8; t++){
        bf16x8 kf = *(const bf16x8*)(&Ks[cur][(t*64 + lane)*8]);
        sa = __builtin_amdgcn_mfma_f32_32x32x16_bf16(kf, qf[t], sa, 0, 0, 0);
      }

      float sv[16];
      if (kt == qw){
        #pragma unroll
        for (int r = 0; r < 16; r++){
          int key = kt + (r&3) + 8*(r>>2) + 4*hl;
          sv[r] = (key > q) ? -1e30f : sa[r]*sm_scale;
        }
      } else {
        #pragma unroll
        for (int r = 0; r < 16; r++) sv[r] = sa[r]*sm_scale;
      }

      float pm = sv[0];
      #pragma unroll
      for (int r = 1; r < 16; r++) pm = fmaxf(pm, sv[r]);
      pm = fmaxf(pm, __shfl_xor(pm, 32));
      if (!__all(pm - m_r <= 8.f)){         // defer-max (T13)
        float mn = fmaxf(m_r, pm);
        float scl = __expf(m_r - mn);
        m_r = mn; l_r *= scl;
        #pragma unroll
        for (int i = 0; i < 4; i++)
          #pragma unroll
          for (int j = 0; j < 16; j++) o[i][j] *= scl;
      }
      float p[16];
      #pragma unroll
      for (int r = 0; r < 16; r++) p[r] = __expf(sv[r] - m_r);
      float ts = 0.f;
      #pragma unroll
      for (int r = 0; r < 16; r++) ts += p[r];
      ts += __shfl_xor(ts, 32);
      l_r += ts;

      uint32_t a0 = cvt_pk_bf16(p[0],  p[1]),  a1 = cvt_pk_bf16(p[2],  p[3]);
      uint32_t a2 = cvt_pk_bf16(p[4],  p[5]),  a3 = cvt_pk_bf16(p[6],  p[7]);
      uint32_t b0 = cvt_pk_bf16(p[8],  p[9]),  b1 = cvt_pk_bf16(p[10], p[11]);
      uint32_t b2 = cvt_pk_bf16(p[12], p[13]), b3 = cvt_pk_bf16(p[14], p[15]);
      pl32swap(a0, a2); pl32swap(a1, a3);
      pl32swap(b0, b2); pl32swap(b1, b3);
      union { uint32_t u[4]; bf16x8 v; } pf0, pf1;
      pf0.u[0]=a0; pf0.u[1]=a1; pf0.u[2]=a2; pf0.u[3]=a3;
      pf1.u[0]=b0; pf1.u[1]=b1; pf1.u[2]=b2; pf1.u[3]=b3;

      #pragma unroll
      for (int db = 0; db < 4; db++){
        bf16x8 vf0 = *(const bf16x8*)(&Vs[cur][((0*4 + db)*64 + lane)*8]);
        o[db] = __builtin_amdgcn_mfma_f32_32x32x16_bf16(vf0, pf0.v, o[db], 0, 0, 0);
        bf16x8 vf1 = *(const bf16x8*)(&Vs[cur][((1*4 + db)*64 + lane)*8]);
        o[db] = __builtin_amdgcn_mfma_f32_32x32x16_bf16(vf1, pf1.v, o[db], 0, 0, 0);
      }
      asm volatile("s_waitcnt lgkmcnt(0)" ::: "memory");
    }
    __builtin_amdgcn_sched_barrier(0);
    __builtin_amdgcn_s_barrier();
    cur ^= 1;
  }

  float inv = 1.f / l_r;
  int b = bh >> 4, hh = bh & 15;
  u16* orow = ao + (size_t)(b*S_ + q)*H_ + hh*HD_;
  #pragma unroll
  for (int db = 0; db < 4; db++){
    #pragma unroll
    for (int g = 0; g < 4; g++){
      ushort4 pk4;
      pk4.x = f2bf(o[db][4*g+0]*inv);
      pk4.y = f2bf(o[db][4*g+1]*inv);
      pk4.z = f2bf(o[db][4*g+2]*inv);
      pk4.w = f2bf(o[db][4*g+3]*inv);
      *(ushort4*)(orow + db*32 + g*8 + hl*4) = pk4;
    }
  }
}

extern "C" void kernel_launch(void* const* d_in, const int* in_sizes, int n_in,
                              void* d_out, int out_size, void* d_ws, size_t ws_size,
                              hipStream_t stream) {
  const float* x      = (const float*)d_in[0];
  const float* rotary = (const float*)d_in[1];
  const float* w_qkv  = (const float*)d_in[2];
  const float* w_o    = (const float*)d_in[3];
  float* out = (float*)d_out;

  char* wsb = (char*)d_ws;
  float* part_qkv = (float*)wsb;             // [1024]
  float* part_o   = part_qkv + 1024;         // [1024]
  float* scales   = part_o + 1024;           // [2]
  size_t off = 16384;
  u16* xb    = (u16*)(wsb + off); off += (size_t)MTOK*H_*2;
  u16* wqkvq = (u16*)(wsb + off); off += (size_t)NQKV*H_*2;
  u16* woq   = (u16*)(wsb + off); off += (size_t)H_*H_*2;
  u16* qbuf  = (u16*)(wsb + off); off += (size_t)B_*NH_*S_*HD_*2;
  u16* kbuf  = (u16*)(wsb + off); off += (size_t)B_*NH_*S_*HD_*2;
  u16* vtb   = (u16*)(wsb + off); off += (size_t)B_*NH_*S_*HD_*2;
  u16* ao    = (u16*)(wsb + off); off += (size_t)MTOK*H_*2;

  absum_kernel<<<1024, 256, 0, stream>>>(w_qkv, 3*H_*H_, part_qkv);
  absum_kernel<<<1024, 256, 0, stream>>>(w_o, H_*H_, part_o);
  finalize_kernel<<<1, 256, 0, stream>>>(part_qkv, part_o, scales);
  quant_kernel<<<4096, 256, 0, stream>>>(w_qkv, wqkvq, 3*H_*H_, scales, 0);
  quant_kernel<<<2048, 256, 0, stream>>>(w_o, woq, H_*H_, scales, 1);
  castx_kernel<<<(MTOK*H_)/256, 256, 0, stream>>>(x, xb, MTOK*H_);

  gemm_kernel<0><<<(MTOK/128)*(NQKV/128), 256, 0, stream>>>(xb, wqkvq, MTOK, NQKV, H_,
                                                            nullptr, qbuf, kbuf, vtb);
  rope_kernel<<<(2*B_*NH_*S_*64)/256, 256, 0, stream>>>(qbuf, kbuf, rotary);
  attn_kernel<<<B_*NH_*(S_/128), 256, 0, stream>>>(qbuf, kbuf, vtb, ao);
  gemm_kernel<1><<<(MTOK/128)*(H_/128), 256, 0, stream>>>(ao, woq, MTOK, H_, H_,
                                                          out, nullptr, nullptr, nullptr);
}

// Round 9
// 381.384 us; speedup vs baseline: 1.2525x; 1.2421x over previous
//
#include <hip/hip_runtime.h>
#include <hip/hip_bf16.h>
#include <stdint.h>

// Problem constants
#define B_   2
#define S_   2048
#define H_   2048
#define NH_  16
#define HD_  128
#define MTOK 4096      // B*S
#define NQKV 6144      // 3*H

typedef unsigned short u16;
typedef __attribute__((ext_vector_type(8))) __bf16 bf16x8;
typedef __attribute__((ext_vector_type(4))) float f32x4;
typedef __attribute__((ext_vector_type(16))) float f32x16;

static __device__ __forceinline__ float bf2f(u16 u){
  union { uint32_t i; float f; } v; v.i = ((uint32_t)u) << 16; return v.f;
}
static __device__ __forceinline__ u16 f2bf(float f){
  union { float f; uint32_t i; } v; v.f = f;
  uint32_t r = v.i + 0x7FFFu + ((v.i >> 16) & 1u);   // RNE
  return (u16)(r >> 16);
}
static __device__ __forceinline__ uint32_t cvt_pk_bf16(float lo, float hi){
  uint32_t r;
  asm("v_cvt_pk_bf16_f32 %0, %1, %2" : "=v"(r) : "v"(lo), "v"(hi));
  return r;
}
static __device__ __forceinline__ void pl32swap(uint32_t &a, uint32_t &b){
  asm volatile("v_permlane32_swap_b32 %0, %1" : "+v"(a), "+v"(b));
}

__device__ __forceinline__ void gload_lds16(const void* g, void* l){
  __builtin_amdgcn_global_load_lds((const __attribute__((address_space(1))) void*)g,
                                   (__attribute__((address_space(3))) void*)l, 16, 0, 0);
}

// ---------- absmean (deterministic two-stage) ----------
__global__ void absum_kernel(const float* __restrict__ w, int n, float* __restrict__ partial){
  __shared__ float sm[256];
  float s = 0.f;
  for (int i = blockIdx.x*256 + threadIdx.x; i < n; i += gridDim.x*256)
    s += fabsf(w[i]);
  sm[threadIdx.x] = s; __syncthreads();
  for (int st = 128; st > 0; st >>= 1){
    if ((int)threadIdx.x < st) sm[threadIdx.x] += sm[threadIdx.x + st];
    __syncthreads();
  }
  if (threadIdx.x == 0) partial[blockIdx.x] = sm[0];
}

__global__ void finalize_kernel(const float* __restrict__ p1, const float* __restrict__ p2,
                                float* __restrict__ scales){
  __shared__ double sm[256];
  int t = threadIdx.x;
  double s = (double)p1[t] + (double)p1[t+256] + (double)p1[t+512] + (double)p1[t+768];
  sm[t] = s; __syncthreads();
  for (int st = 128; st > 0; st >>= 1){ if (t < st) sm[t] += sm[t+st]; __syncthreads(); }
  if (t == 0) scales[0] = (float)(1.0 / (sm[0] / (double)(3*H_*H_) + 1e-5));
  __syncthreads();
  s = (double)p2[t] + (double)p2[t+256] + (double)p2[t+512] + (double)p2[t+768];
  sm[t] = s; __syncthreads();
  for (int st = 128; st > 0; st >>= 1){ if (t < st) sm[t] += sm[t+st]; __syncthreads(); }
  if (t == 0) scales[1] = (float)(1.0 / (sm[0] / (double)(H_*H_) + 1e-5));
}

// ---------- ternary quantize to bf16 {-1,0,1} ----------
__global__ void quant_kernel(const float* __restrict__ w, u16* __restrict__ wq, int n,
                             const float* __restrict__ scales, int which){
  float inv = scales[which];
  for (int i = blockIdx.x*256 + threadIdx.x; i < n; i += gridDim.x*256){
    float q = rintf(w[i] * inv);
    q = fminf(1.f, fmaxf(-1.f, q));
    wq[i] = f2bf(q);
  }
}

__global__ void castx_kernel(const float* __restrict__ x, u16* __restrict__ xb, int n){
  int i = blockIdx.x*256 + threadIdx.x;
  if (i < n) xb[i] = f2bf(x[i]);
}

// ---------- GEMM C = A * B^T, 128x128 tile, BK=32, 4 waves (R4 structure) ----------
// Byte-identical to the 191us R4 kernel except __launch_bounds__(256, 4):
// R4's combined reg use was 68 VGPR + 64 AGPR = 132, 4 over the 128 cliff
// (waves/SIMD halve at 64/128/256) -> 3 waves/SIMD. Forcing 4 waves/EU caps
// combined at 128 -> 4 waves/SIMD, +33% resident overlap.
template<int EPI>
__global__ __launch_bounds__(256, 4) void gemm_kernel(const u16* __restrict__ A,
    const u16* __restrict__ Bw, int M, int N, int K,
    float* __restrict__ outf, u16* __restrict__ qb, u16* __restrict__ kb, u16* __restrict__ vtb)
{
  __shared__ u16 As[128*32];
  __shared__ u16 Bs[128*32];
  int nbn = N >> 7;
  int nb_tot = (M >> 7) * nbn;
  int bid = blockIdx.x;
  int chunk = nb_tot >> 3;
  bid = (bid & 7) * chunk + (bid >> 3);    // XCD-contiguous swizzle (bijective)
  int bm = bid / nbn, bn = bid % nbn;
  int m0 = bm << 7, n0 = bn << 7;
  int tid = threadIdx.x;
  int lane = tid & 63, wid = tid >> 6;
  int wr = wid >> 1, wc = wid & 1;
  int lg = lane >> 4, lr = lane & 15;

  const u16* Ab = A + m0 * K;
  const u16* Bb = Bw + n0 * K;
  int srow = tid >> 2;
  int scol = (tid & 3) << 3;

  f32x4 acc[4][4];
  #pragma unroll
  for (int i = 0; i < 4; i++)
    #pragma unroll
    for (int j = 0; j < 4; j++) acc[i][j] = f32x4{0.f,0.f,0.f,0.f};

  for (int k0 = 0; k0 < K; k0 += 32){
    gload_lds16(Ab + srow*K      + k0 + scol, As + tid*8);
    gload_lds16(Ab + (srow+64)*K + k0 + scol, As + 2048 + tid*8);
    gload_lds16(Bb + srow*K      + k0 + scol, Bs + tid*8);
    gload_lds16(Bb + (srow+64)*K + k0 + scol, Bs + 2048 + tid*8);
    __syncthreads();
    bf16x8 af[4], bfr[4];
    #pragma unroll
    for (int mi = 0; mi < 4; mi++) af[mi]  = *(const bf16x8*)(As + ((wr*64 + mi*16 + lr)*32 + lg*8));
    #pragma unroll
    for (int ni = 0; ni < 4; ni++) bfr[ni] = *(const bf16x8*)(Bs + ((wc*64 + ni*16 + lr)*32 + lg*8));
    #pragma unroll
    for (int mi = 0; mi < 4; mi++)
      #pragma unroll
      for (int ni = 0; ni < 4; ni++)
        acc[mi][ni] = __builtin_amdgcn_mfma_f32_16x16x32_bf16(af[mi], bfr[ni], acc[mi][ni], 0, 0, 0);
    __syncthreads();
  }

  #pragma unroll
  for (int mi = 0; mi < 4; mi++){
    #pragma unroll
    for (int ni = 0; ni < 4; ni++){
      int ncol = n0 + wc*64 + ni*16 + lr;
      #pragma unroll
      for (int r = 0; r < 4; r++){
        int m = m0 + wr*64 + mi*16 + lg*4 + r;
        float v = acc[mi][ni][r] * 0.0625f;           // /16
        v = fminf(128.f, fmaxf(-128.f, v));
        if (EPI == 1){
          outf[m*N + ncol] = v;
        } else {
          int b = m >> 11, s = m & 2047;
          int part = ncol >> 11, c = ncol & 2047;
          int h = c >> 7, d = c & 127;
          int bh = b*NH_ + h;
          u16 bv = f2bf(v);
          if (part == 0)      qb[((bh*S_ + s) << 7) + d] = bv;
          else if (part == 1) kb[((bh*S_ + s) << 7) + d] = bv;
          else                vtb[((bh*HD_ + d) << 11) + s] = bv;  // V transposed
        }
      }
    }
  }
}

// ---------- RoPE in place on q,k [B*NH, S, HD] ----------
__global__ void rope_kernel(u16* __restrict__ qb, u16* __restrict__ kb, const float* __restrict__ rot){
  int i = blockIdx.x*256 + threadIdx.x;
  int d = i & 63;
  int s = (i >> 6) & 2047;
  int bh = (i >> 17) & 31;
  u16* buf = (i >> 22) ? kb : qb;
  int base = (bh*S_ + s)*HD_;
  float c  = rot[s*HD_ + d];
  float sn = rot[S_*HD_ + s*HD_ + d];
  float x1 = bf2f(buf[base + d]);
  float x2 = bf2f(buf[base + d + 64]);
  buf[base + d]      = f2bf(x1*c - x2*sn);
  buf[base + d + 64] = f2bf(x2*c + x1*sn);
}

// ---------- causal flash attention: 4 waves x 32 q-rows, 32x32x16 MFMA ----------
__global__ __launch_bounds__(256) void attn_kernel(const u16* __restrict__ qb,
    const u16* __restrict__ kb, const u16* __restrict__ vtb, u16* __restrict__ ao)
{
  __shared__ alignas(16) u16 Ks[2][4096];
  __shared__ alignas(16) u16 Vs[2][4096];

  int bid = blockIdx.x;                     // 512 blocks
  int sbid = (bid & 7)*64 + (bid >> 3);     // XCD swizzle
  int bh = sbid >> 4;
  int bq = 15 - (sbid & 15);                // longest q-blocks dispatch first
  int tid = threadIdx.x;
  int wid = tid >> 6, lane = tid & 63;
  int l31 = lane & 31, hl = lane >> 5;
  int q0 = bq * 128;
  int qw = q0 + wid*32;
  int q  = qw + l31;

  const u16* Qp = qb + (size_t)(bh*S_ + qw)*HD_;
  const u16* Kp = kb + (size_t)bh*S_*HD_;
  const u16* Vt = vtb + (size_t)bh*HD_*S_;

  bf16x8 qf[8];
  #pragma unroll
  for (int t = 0; t < 8; t++)
    qf[t] = *(const bf16x8*)(Qp + l31*HD_ + t*16 + hl*8);

  f32x16 o[4];
  #pragma unroll
  for (int i = 0; i < 4; i++)
    #pragma unroll
    for (int j = 0; j < 16; j++) o[i][j] = 0.f;
  float m_r = -1e30f, l_r = 0.f;
  const float sm_scale = 0.08838834764831845f;

  auto STAGE = [&](int buf, int kt2){
    int t0 = wid*2;
    gload_lds16(Kp + (size_t)(kt2 + l31)*HD_ + (t0  )*16 + hl*8, &Ks[buf][((t0  )*64 + lane)*8]);
    gload_lds16(Kp + (size_t)(kt2 + l31)*HD_ + (t0+1)*16 + hl*8, &Ks[buf][((t0+1)*64 + lane)*8]);
    int v0 = wid*2, v1 = wid*2 + 1;
    gload_lds16(Vt + (size_t)((v0&3)*32 + l31)*S_ + kt2 + (v0>>2)*16 + hl*8, &Vs[buf][(v0*64 + lane)*8]);
    gload_lds16(Vt + (size_t)((v1&3)*32 + l31)*S_ + kt2 + (v1>>2)*16 + hl*8, &Vs[buf][(v1*64 + lane)*8]);
  };

  int n_it = 4*bq + 4;
  STAGE(0, 0);
  int cur = 0, kt = 0;
  for (int it = 0; it < n_it; ++it, kt += 32){
    if (it + 1 < n_it){
      STAGE(cur ^ 1, kt + 32);
      asm volatile("s_waitcnt vmcnt(4)" ::: "memory");
    } else {
      asm volatile("s_waitcnt vmcnt(0)" ::: "memory");
    }
    __builtin_amdgcn_sched_barrier(0);
    __builtin_amdgcn_s_barrier();

    if (kt <= qw){
      f32x16 sa;
      #pragma unroll
      for (int j = 0; j < 16; j++) sa[j] = 0.f;
      #pragma unroll
      for (int t = 0; t < 8; t++){
        bf16x8 kf = *(const bf16x8*)(&Ks[cur][(t*64 + lane)*8]);
        sa = __builtin_amdgcn_mfma_f32_32x32x16_bf16(kf, qf[t], sa, 0, 0, 0);
      }

      float sv[16];
      if (kt == qw){
        #pragma unroll
        for (int r = 0; r < 16; r++){
          int key = kt + (r&3) + 8*(r>>2) + 4*hl;
          sv[r] = (key > q) ? -1e30f : sa[r]*sm_scale;
        }
      } else {
        #pragma unroll
        for (int r = 0; r < 16; r++) sv[r] = sa[r]*sm_scale;
      }

      float pm = sv[0];
      #pragma unroll
      for (int r = 1; r < 16; r++) pm = fmaxf(pm, sv[r]);
      pm = fmaxf(pm, __shfl_xor(pm, 32));
      if (!__all(pm - m_r <= 8.f)){         // defer-max (T13)
        float mn = fmaxf(m_r, pm);
        float scl = __expf(m_r - mn);
        m_r = mn; l_r *= scl;
        #pragma unroll
        for (int i = 0; i < 4; i++)
          #pragma unroll
          for (int j = 0; j < 16; j++) o[i][j] *= scl;
      }
      float p[16];
      #pragma unroll
      for (int r = 0; r < 16; r++) p[r] = __expf(sv[r] - m_r);
      float ts = 0.f;
      #pragma unroll
      for (int r = 0; r < 16; r++) ts += p[r];
      ts += __shfl_xor(ts, 32);
      l_r += ts;

      uint32_t a0 = cvt_pk_bf16(p[0],  p[1]),  a1 = cvt_pk_bf16(p[2],  p[3]);
      uint32_t a2 = cvt_pk_bf16(p[4],  p[5]),  a3 = cvt_pk_bf16(p[6],  p[7]);
      uint32_t b0 = cvt_pk_bf16(p[8],  p[9]),  b1 = cvt_pk_bf16(p[10], p[11]);
      uint32_t b2 = cvt_pk_bf16(p[12], p[13]), b3 = cvt_pk_bf16(p[14], p[15]);
      pl32swap(a0, a2); pl32swap(a1, a3);
      pl32swap(b0, b2); pl32swap(b1, b3);
      union { uint32_t u[4]; bf16x8 v; } pf0, pf1;
      pf0.u[0]=a0; pf0.u[1]=a1; pf0.u[2]=a2; pf0.u[3]=a3;
      pf1.u[0]=b0; pf1.u[1]=b1; pf1.u[2]=b2; pf1.u[3]=b3;

      #pragma unroll
      for (int db = 0; db < 4; db++){
        bf16x8 vf0 = *(const bf16x8*)(&Vs[cur][((0*4 + db)*64 + lane)*8]);
        o[db] = __builtin_amdgcn_mfma_f32_32x32x16_bf16(vf0, pf0.v, o[db], 0, 0, 0);
        bf16x8 vf1 = *(const bf16x8*)(&Vs[cur][((1*4 + db)*64 + lane)*8]);
        o[db] = __builtin_amdgcn_mfma_f32_32x32x16_bf16(vf1, pf1.v, o[db], 0, 0, 0);
      }
      asm volatile("s_waitcnt lgkmcnt(0)" ::: "memory");
    }
    __builtin_amdgcn_sched_barrier(0);
    __builtin_amdgcn_s_barrier();
    cur ^= 1;
  }

  float inv = 1.f / l_r;
  int b = bh >> 4, hh = bh & 15;
  u16* orow = ao + (size_t)(b*S_ + q)*H_ + hh*HD_;
  #pragma unroll
  for (int db = 0; db < 4; db++){
    #pragma unroll
    for (int g = 0; g < 4; g++){
      ushort4 pk4;
      pk4.x = f2bf(o[db][4*g+0]*inv);
      pk4.y = f2bf(o[db][4*g+1]*inv);
      pk4.z = f2bf(o[db][4*g+2]*inv);
      pk4.w = f2bf(o[db][4*g+3]*inv);
      *(ushort4*)(orow + db*32 + g*8 + hl*4) = pk4;
    }
  }
}

extern "C" void kernel_launch(void* const* d_in, const int* in_sizes, int n_in,
                              void* d_out, int out_size, void* d_ws, size_t ws_size,
                              hipStream_t stream) {
  const float* x      = (const float*)d_in[0];
  const float* rotary = (const float*)d_in[1];
  const float* w_qkv  = (const float*)d_in[2];
  const float* w_o    = (const float*)d_in[3];
  float* out = (float*)d_out;

  char* wsb = (char*)d_ws;
  float* part_qkv = (float*)wsb;             // [1024]
  float* part_o   = part_qkv + 1024;         // [1024]
  float* scales   = part_o + 1024;           // [2]
  size_t off = 16384;
  u16* xb    = (u16*)(wsb + off); off += (size_t)MTOK*H_*2;
  u16* wqkvq = (u16*)(wsb + off); off += (size_t)NQKV*H_*2;
  u16* woq   = (u16*)(wsb + off); off += (size_t)H_*H_*2;
  u16* qbuf  = (u16*)(wsb + off); off += (size_t)B_*NH_*S_*HD_*2;
  u16* kbuf  = (u16*)(wsb + off); off += (size_t)B_*NH_*S_*HD_*2;
  u16* vtb   = (u16*)(wsb + off); off += (size_t)B_*NH_*S_*HD_*2;
  u16* ao    = (u16*)(wsb + off); off += (size_t)MTOK*H_*2;

  absum_kernel<<<1024, 256, 0, stream>>>(w_qkv, 3*H_*H_, part_qkv);
  absum_kernel<<<1024, 256, 0, stream>>>(w_o, H_*H_, part_o);
  finalize_kernel<<<1, 256, 0, stream>>>(part_qkv, part_o, scales);
  quant_kernel<<<4096, 256, 0, stream>>>(w_qkv, wqkvq, 3*H_*H_, scales, 0);
  quant_kernel<<<2048, 256, 0, stream>>>(w_o, woq, H_*H_, scales, 1);
  castx_kernel<<<(MTOK*H_)/256, 256, 0, stream>>>(x, xb, MTOK*H_);

  gemm_kernel<0><<<(MTOK/128)*(NQKV/128), 256, 0, stream>>>(xb, wqkvq, MTOK, NQKV, H_,
                                                            nullptr, qbuf, kbuf, vtb);
  rope_kernel<<<(2*B_*NH_*S_*64)/256, 256, 0, stream>>>(qbuf, kbuf, rotary);
  attn_kernel<<<B_*NH_*(S_/128), 256, 0, stream>>>(qbuf, kbuf, vtb, ao);
  gemm_kernel<1><<<(MTOK/128)*(H_/128), 256, 0, stream>>>(ao, woq, MTOK, H_, H_,
                                                          out, nullptr, nullptr, nullptr);
}